// Round 15
// baseline (781.850 us; speedup 1.0000x reference)
//
#include <hip/hip_runtime.h>
#include <stdint.h>
#include <math.h>

typedef unsigned short ushort_t;
typedef __attribute__((ext_vector_type(8))) short short8;
typedef __attribute__((ext_vector_type(4))) float f32x4;

#define T_ 1024
#define HID_ 2048
#define NH_ 32
#define NKV_ 8
#define HD_ 64
#define QS_ 2048
#define KVS_ 512
#define QKVN_ 3072
#define NEXP_ 32
#define TOPK_ 4
#define FF_ 1792
#define FF2_ 3584
#define CAP_ 256
#define EPS_ 1e-5f
#define ATT_SCALE_ 0.125f

__device__ __forceinline__ ushort_t f2bf(float f) {
    uint32_t u = __builtin_bit_cast(uint32_t, f);
    u += 0x7FFFu + ((u >> 16) & 1u);
    return (ushort_t)(u >> 16);
}

__device__ __forceinline__ float bf2f(ushort_t u) {
    uint32_t x = ((uint32_t)u) << 16;
    return __builtin_bit_cast(float, x);
}

__device__ __forceinline__ f32x4 mfma16(short8 a, short8 b, f32x4 c) {
    return __builtin_amdgcn_mfma_f32_16x16x32_bf16(a, b, c, 0, 0, 0);
}

// pack two f32 -> {bf16(lo), bf16(hi)} in one uint32 (low half = lo)
__device__ __forceinline__ uint32_t cvtpk(float lo, float hi) {
    uint32_t r;
    asm("v_cvt_pk_bf16_f32 %0, %1, %2" : "=v"(r) : "v"(lo), "v"(hi));
    return r;
}

// ---------------- add + rmsnorm ----------------
__global__ __launch_bounds__(256) void k_addnorm(
    const float* __restrict__ a, const float* __restrict__ b,
    const float* __restrict__ w, float* __restrict__ res_out,
    float* __restrict__ hf, ushort_t* __restrict__ hb)
{
    __shared__ float sred[4];
    const int t = blockIdx.x;
    float x[8];
    float ss = 0.f;
#pragma unroll
    for (int i = 0; i < 8; i++) {
        int c = threadIdx.x + i * 256;
        float v = a[(size_t)t * HID_ + c];
        if (b) v += b[(size_t)t * HID_ + c];
        x[i] = v;
        ss += v * v;
    }
    ss += __shfl_xor(ss, 1);  ss += __shfl_xor(ss, 2);  ss += __shfl_xor(ss, 4);
    ss += __shfl_xor(ss, 8);  ss += __shfl_xor(ss, 16); ss += __shfl_xor(ss, 32);
    const int lane = threadIdx.x & 63, wv = threadIdx.x >> 6;
    if (lane == 0) sred[wv] = ss;
    __syncthreads();
    ss = sred[0] + sred[1] + sred[2] + sred[3];
    const float scale = rsqrtf(ss * (1.0f / HID_) + EPS_);
#pragma unroll
    for (int i = 0; i < 8; i++) {
        int c = threadIdx.x + i * 256;
        if (res_out) res_out[(size_t)t * HID_ + c] = x[i];
        float hv = x[i] * scale * w[c];
        if (hf) hf[(size_t)t * HID_ + c] = hv;
        hb[(size_t)t * HID_ + c] = f2bf(hv);
    }
}

// ---------------- rope tables ----------------
__global__ __launch_bounds__(256) void k_rope_table(const int* __restrict__ positions,
                                                    float* __restrict__ cosb, float* __restrict__ sinb)
{
    int idx = blockIdx.x * 256 + threadIdx.x;
    if (idx >= T_ * 32) return;
    int t = idx >> 5, f = idx & 31;
    double invf = pow(1.0e6, -((double)f) / 32.0);
    double ang = (double)positions[t] * invf;
    cosb[idx] = (float)cos(ang);
    sinb[idx] = (float)sin(ang);
}

// ---------------- q/k head-rmsnorm + rope, v transpose ----------------
__global__ __launch_bounds__(256) void k_qkv_post(
    const float* __restrict__ qkv, const float* __restrict__ qw, const float* __restrict__ kw,
    const float* __restrict__ cosb, const float* __restrict__ sinb,
    ushort_t* __restrict__ qr, ushort_t* __restrict__ kc, ushort_t* __restrict__ vT)
{
    const int t = blockIdx.x;
    const int wv = threadIdx.x >> 6, lane = threadIdx.x & 63;
    const float* row = qkv + (size_t)t * QKVN_;
    const float c = cosb[t * 32 + (lane & 31)];
    const float s = sinb[t * 32 + (lane & 31)];
#pragma unroll
    for (int i = 0; i < 8; i++) {
        int hh = wv + i * 4;
        float x = row[hh * 64 + lane];
        float ss = x * x;
        ss += __shfl_xor(ss, 1); ss += __shfl_xor(ss, 2); ss += __shfl_xor(ss, 4);
        ss += __shfl_xor(ss, 8); ss += __shfl_xor(ss, 16); ss += __shfl_xor(ss, 32);
        float xn = x * rsqrtf(ss * (1.0f / 64.0f) + EPS_) * qw[lane];
        float other = __shfl_xor(xn, 32);
        float o = (lane < 32) ? (xn * c - other * s) : (xn * c + other * s);
        qr[(size_t)t * QS_ + hh * 64 + lane] = f2bf(o);
    }
#pragma unroll
    for (int i = 0; i < 2; i++) {
        int kh = wv * 2 + i;
        float x = row[QS_ + kh * 64 + lane];
        float ss = x * x;
        ss += __shfl_xor(ss, 1); ss += __shfl_xor(ss, 2); ss += __shfl_xor(ss, 4);
        ss += __shfl_xor(ss, 8); ss += __shfl_xor(ss, 16); ss += __shfl_xor(ss, 32);
        float xn = x * rsqrtf(ss * (1.0f / 64.0f) + EPS_) * kw[lane];
        float other = __shfl_xor(xn, 32);
        float o = (lane < 32) ? (xn * c - other * s) : (xn * c + other * s);
        kc[((size_t)kh * T_ + t) * 64 + lane] = f2bf(o);
    }
#pragma unroll
    for (int i = 0; i < 2; i++) {
        int idx = threadIdx.x + i * 256;
        int kh = idx >> 6, d = idx & 63;
        vT[((size_t)kh * 64 + d) * T_ + t] = f2bf(row[QS_ + KVS_ + idx]);
    }
}

// ---------------- causal GQA flash attention ----------------
__global__ __launch_bounds__(256) void k_attn(
    const ushort_t* __restrict__ qr, const ushort_t* __restrict__ kc,
    const ushort_t* __restrict__ vT, ushort_t* __restrict__ aout)
{
    __shared__ float p_lds[4][16][36];
    const int head = blockIdx.y;
    const int qb = blockIdx.x * 64;
    const int wv = threadIdx.x >> 6, lane = threadIdx.x & 63;
    const int lr = lane & 15, lg = lane >> 4;
    const int kvh = head >> 2;
    const int qbase = qb + wv * 16;

    const ushort_t* qp = qr + (size_t)(qbase + lr) * QS_ + head * 64 + lg * 8;
    short8 qf0 = *(const short8*)qp;
    short8 qf1 = *(const short8*)(qp + 32);

    f32x4 o[4];
#pragma unroll
    for (int i = 0; i < 4; i++) o[i] = (f32x4){0.f, 0.f, 0.f, 0.f};
    float mrow[4] = {-INFINITY, -INFINITY, -INFINITY, -INFINITY};
    float lrow[4] = {0.f, 0.f, 0.f, 0.f};

    const int ntile = ((qbase + 15) >> 5) + 1;
    for (int tt = 0; tt < ntile; tt++) {
        const int kv0 = tt * 32;
        const ushort_t* kp = kc + ((size_t)kvh * T_ + kv0) * 64;
        short8 b00 = *(const short8*)(kp + lr * 64 + lg * 8);
        short8 b01 = *(const short8*)(kp + lr * 64 + 32 + lg * 8);
        short8 b10 = *(const short8*)(kp + (16 + lr) * 64 + lg * 8);
        short8 b11 = *(const short8*)(kp + (16 + lr) * 64 + 32 + lg * 8);
        f32x4 s0 = {0.f, 0.f, 0.f, 0.f}, s1 = {0.f, 0.f, 0.f, 0.f};
        s0 = mfma16(qf0, b00, s0); s0 = mfma16(qf1, b01, s0);
        s1 = mfma16(qf0, b10, s1); s1 = mfma16(qf1, b11, s1);

        float p0[4], p1[4], alpha[4];
#pragma unroll
        for (int r = 0; r < 4; r++) {
            int qrow = qbase + lg * 4 + r;
            float v0 = (kv0 + lr <= qrow) ? s0[r] * ATT_SCALE_ : -INFINITY;
            float v1 = (kv0 + 16 + lr <= qrow) ? s1[r] * ATT_SCALE_ : -INFINITY;
            float mx = fmaxf(v0, v1);
            mx = fmaxf(mx, __shfl_xor(mx, 1));
            mx = fmaxf(mx, __shfl_xor(mx, 2));
            mx = fmaxf(mx, __shfl_xor(mx, 4));
            mx = fmaxf(mx, __shfl_xor(mx, 8));
            float mn = fmaxf(mrow[r], mx);
            float al = (mrow[r] == -INFINITY) ? 0.f : __expf(mrow[r] - mn);
            float pv0 = (v0 == -INFINITY) ? 0.f : __expf(v0 - mn);
            float pv1 = (v1 == -INFINITY) ? 0.f : __expf(v1 - mn);
            float ps = pv0 + pv1;
            ps += __shfl_xor(ps, 1); ps += __shfl_xor(ps, 2);
            ps += __shfl_xor(ps, 4); ps += __shfl_xor(ps, 8);
            lrow[r] = lrow[r] * al + ps;
            mrow[r] = mn;
            alpha[r] = al; p0[r] = pv0; p1[r] = pv1;
        }
#pragma unroll
        for (int r = 0; r < 4; r++) {
            p_lds[wv][lg * 4 + r][lr] = p0[r];
            p_lds[wv][lg * 4 + r][16 + lr] = p1[r];
            o[0][r] *= alpha[r]; o[1][r] *= alpha[r];
            o[2][r] *= alpha[r]; o[3][r] *= alpha[r];
        }
        asm volatile("s_waitcnt lgkmcnt(0)" ::: "memory");
        float4 pa0 = *(const float4*)&p_lds[wv][lr][lg * 8];
        float4 pa1 = *(const float4*)&p_lds[wv][lr][lg * 8 + 4];
        short8 pf;
        pf[0] = (short)f2bf(pa0.x); pf[1] = (short)f2bf(pa0.y);
        pf[2] = (short)f2bf(pa0.z); pf[3] = (short)f2bf(pa0.w);
        pf[4] = (short)f2bf(pa1.x); pf[5] = (short)f2bf(pa1.y);
        pf[6] = (short)f2bf(pa1.z); pf[7] = (short)f2bf(pa1.w);
#pragma unroll
        for (int dg = 0; dg < 4; dg++) {
            short8 vf = *(const short8*)(vT + ((size_t)(kvh * 64 + dg * 16 + lr)) * T_ + kv0 + lg * 8);
            o[dg] = mfma16(pf, vf, o[dg]);
        }
    }
#pragma unroll
    for (int dg = 0; dg < 4; dg++)
#pragma unroll
        for (int r = 0; r < 4; r++)
            aout[(size_t)(qbase + lg * 4 + r) * HID_ + head * 64 + dg * 16 + lr] =
                f2bf(o[dg][r] / lrow[r]);
}

// ---------------- 128x64 GEMM, BK=128, in-phase staging ----------------
// 1D grid with XCD swizzle. MODE 0: C = acc ; MODE 1: C = acc + resid
template <int MODE>
__global__ __launch_bounds__(256) void k_gemm128(
    const ushort_t* __restrict__ A, const float* __restrict__ B,
    float* __restrict__ C, const float* __restrict__ resid, int N, int K, int nnb)
{
    const int nwg8 = (gridDim.x >> 3);
    const int d = blockIdx.x;
    const int wg = (d & 7) * nwg8 + (d >> 3);
    const int mbase = (wg / nnb) * 128, nbase = (wg % nnb) * 64;

    __shared__ ushort_t As[128][136];  // 128 x 128k (+8 pad)
    __shared__ ushort_t Bs[64][136];   // [n][k]
    const int tid = threadIdx.x;
    const int lane = tid & 63, wv = tid >> 6;
    const int lr = lane & 15, lg = lane >> 4;
    const int wm = wv >> 1, wn = wv & 1;

    f32x4 acc[4][2];
#pragma unroll
    for (int i = 0; i < 4; i++)
#pragma unroll
        for (int j = 0; j < 2; j++) acc[i][j] = (f32x4){0.f, 0.f, 0.f, 0.f};

    const int arow0 = tid >> 4, achk = tid & 15;     // 16 base rows x 16 chunks
    const int bk0 = (tid & 15) * 2, bnq = tid >> 4;  // k-pair, n-quad [0,16)
    const int bcol = nbase + bnq * 4;
    const int brow = bnq * 4;

    for (int kb = 0; kb < K; kb += 128) {
        // B: 4 k-strips, loaded & converted sequentially (in-phase)
#pragma unroll
        for (int ks = 0; ks < 4; ks++) {
            const int ko = ks * 32;
            float4 bA = *(const float4*)(B + (size_t)(kb + ko + bk0) * N + bcol);
            float4 bB = *(const float4*)(B + (size_t)(kb + ko + bk0 + 1) * N + bcol);
            *(uint32_t*)&Bs[brow + 0][bk0 + ko] = cvtpk(bA.x, bB.x);
            *(uint32_t*)&Bs[brow + 1][bk0 + ko] = cvtpk(bA.y, bB.y);
            *(uint32_t*)&Bs[brow + 2][bk0 + ko] = cvtpk(bA.z, bB.z);
            *(uint32_t*)&Bs[brow + 3][bk0 + ko] = cvtpk(bA.w, bB.w);
        }
        // A: 8 row-groups of 16
        {
            uint4 areg[8];
#pragma unroll
            for (int i = 0; i < 8; i++)
                areg[i] = *(const uint4*)(A + (size_t)(mbase + arow0 + i * 16) * K + kb + achk * 8);
#pragma unroll
            for (int i = 0; i < 8; i++)
                *(uint4*)&As[arow0 + i * 16][achk * 8] = areg[i];
        }
        __syncthreads();
#pragma unroll
        for (int kk = 0; kk < 4; kk++) {
            short8 af[4], bfr[2];
#pragma unroll
            for (int mi = 0; mi < 4; mi++)
                af[mi] = *(const short8*)&As[wm * 64 + mi * 16 + lr][kk * 32 + lg * 8];
#pragma unroll
            for (int ni = 0; ni < 2; ni++)
                bfr[ni] = *(const short8*)&Bs[wn * 32 + ni * 16 + lr][kk * 32 + lg * 8];
#pragma unroll
            for (int mi = 0; mi < 4; mi++)
#pragma unroll
                for (int ni = 0; ni < 2; ni++)
                    acc[mi][ni] = mfma16(af[mi], bfr[ni], acc[mi][ni]);
        }
        __syncthreads();
    }
#pragma unroll
    for (int mi = 0; mi < 4; mi++)
#pragma unroll
        for (int ni = 0; ni < 2; ni++)
#pragma unroll
            for (int r = 0; r < 4; r++) {
                int row = mbase + wm * 64 + mi * 16 + lg * 4 + r;
                int col = nbase + wn * 32 + ni * 16 + lr;
                float v = acc[mi][ni][r];
                if (MODE == 1) v += resid[(size_t)row * N + col];
                C[(size_t)row * N + col] = v;
            }
}

// ---------------- MoE gu GEMM: M=256/expert, N=64g+64u, BK=64 ----------------
// In-phase staging; kk-scoped fragments cap live registers. (R10 gu, isolated A/B.)
__global__ __launch_bounds__(256) void k_moe_gu(
    const ushort_t* __restrict__ h2b, const int* __restrict__ etok,
    const int* __restrict__ ecnt, const float* __restrict__ w1,
    ushort_t* __restrict__ hact)
{
    const int d = blockIdx.x;                    // 896 = 32e * 28n, XCD-swizzled
    const int wg = (d & 7) * 112 + (d >> 3);
    const int e = wg / 28, ny = wg - e * 28;
    const int cnt = ecnt[e];
    if (cnt == 0) return;
    const int ng0 = ny * 64;
    const float* B = w1 + (size_t)e * HID_ * FF2_;

    __shared__ ushort_t As[256][72];   // 256 x 64k (+8 pad)
    __shared__ ushort_t Bs[128][72];   // rows 0-63: g, 64-127: u
    const int tid = threadIdx.x;
    const int lane = tid & 63, wv = tid >> 6;
    const int lr = lane & 15, lg = lane >> 4;

    const int arow0 = tid >> 3, achk = tid & 7;  // 32 base-rows x 8 k-chunks
    int tok[8];
#pragma unroll
    for (int i = 0; i < 8; i++) {
        int r = arow0 + i * 32;
        tok[i] = (r < cnt) ? etok[e * CAP_ + r] : 0;
    }
    const int half = tid >> 7;                   // 0: g, 1: u
    const int t7 = tid & 127;
    const int bk0 = (t7 & 15) * 2, bnq = t7 >> 4;  // k-pair, n-quad [0,8)
    const size_t bcolA = (half ? FF_ : 0) + ng0 + bnq * 4;
    const size_t bcolB = bcolA + 32;
    const int browA = half * 64 + bnq * 4;
    const int browB = browA + 32;

    f32x4 ag[4][4], au[4][4];
#pragma unroll
    for (int i = 0; i < 4; i++)
#pragma unroll
        for (int j = 0; j < 4; j++) { ag[i][j] = (f32x4){0.f,0.f,0.f,0.f}; au[i][j] = (f32x4){0.f,0.f,0.f,0.f}; }

    for (int kb = 0; kb < HID_; kb += 64) {
        // stage B: two n-quads x two k-strips, all in-phase
#pragma unroll
        for (int ks = 0; ks < 2; ks++) {
            const int ko = ks * 32;
            float4 bA0 = *(const float4*)(B + (size_t)(kb + ko + bk0) * FF2_ + bcolA);
            float4 bB0 = *(const float4*)(B + (size_t)(kb + ko + bk0 + 1) * FF2_ + bcolA);
            float4 bA1 = *(const float4*)(B + (size_t)(kb + ko + bk0) * FF2_ + bcolB);
            float4 bB1 = *(const float4*)(B + (size_t)(kb + ko + bk0 + 1) * FF2_ + bcolB);
            *(uint32_t*)&Bs[browA + 0][bk0 + ko] = cvtpk(bA0.x, bB0.x);
            *(uint32_t*)&Bs[browA + 1][bk0 + ko] = cvtpk(bA0.y, bB0.y);
            *(uint32_t*)&Bs[browA + 2][bk0 + ko] = cvtpk(bA0.z, bB0.z);
            *(uint32_t*)&Bs[browA + 3][bk0 + ko] = cvtpk(bA0.w, bB0.w);
            *(uint32_t*)&Bs[browB + 0][bk0 + ko] = cvtpk(bA1.x, bB1.x);
            *(uint32_t*)&Bs[browB + 1][bk0 + ko] = cvtpk(bA1.y, bB1.y);
            *(uint32_t*)&Bs[browB + 2][bk0 + ko] = cvtpk(bA1.z, bB1.z);
            *(uint32_t*)&Bs[browB + 3][bk0 + ko] = cvtpk(bA1.w, bB1.w);
        }
        {
            uint4 areg[8];
#pragma unroll
            for (int i = 0; i < 8; i++)
                areg[i] = *(const uint4*)(h2b + (size_t)tok[i] * HID_ + kb + achk * 8);
#pragma unroll
            for (int i = 0; i < 8; i++)
                *(uint4*)&As[arow0 + i * 32][achk * 8] = areg[i];
        }
        __syncthreads();
        // kk-scoped fragments: <=48 frag regs live at a time
#pragma unroll
        for (int kk = 0; kk < 2; kk++) {
            short8 af[4], bg[4], bu[4];
#pragma unroll
            for (int mi = 0; mi < 4; mi++)
                af[mi] = *(const short8*)&As[wv * 64 + mi * 16 + lr][kk * 32 + lg * 8];
#pragma unroll
            for (int ni = 0; ni < 4; ni++) {
                bg[ni] = *(const short8*)&Bs[ni * 16 + lr][kk * 32 + lg * 8];
                bu[ni] = *(const short8*)&Bs[64 + ni * 16 + lr][kk * 32 + lg * 8];
            }
#pragma unroll
            for (int mi = 0; mi < 4; mi++)
#pragma unroll
                for (int ni = 0; ni < 4; ni++) {
                    ag[mi][ni] = mfma16(af[mi], bg[ni], ag[mi][ni]);
                    au[mi][ni] = mfma16(af[mi], bu[ni], au[mi][ni]);
                }
        }
        __syncthreads();
    }
#pragma unroll
    for (int mi = 0; mi < 4; mi++)
#pragma unroll
        for (int ni = 0; ni < 4; ni++)
#pragma unroll
            for (int r = 0; r < 4; r++) {
                int row = wv * 64 + mi * 16 + lg * 4 + r;
                int col = ng0 + ni * 16 + lr;
                float g = ag[mi][ni][r], u = au[mi][ni][r];
                float hval = (g / (1.0f + __expf(-g))) * u;
                hact[((size_t)e * CAP_ + row) * FF_ + col] = f2bf(hval);
            }
}

// ---------------- MoE w2 GEMM: M=256/expert, N-tile 64, BK=64 ----------------
__global__ __launch_bounds__(256) void k_moe_w2(
    const ushort_t* __restrict__ hact, const float* __restrict__ w2,
    const int* __restrict__ ecnt, ushort_t* __restrict__ eo)
{
    const int d = blockIdx.x;                    // 1024 = 32e * 32n, XCD-swizzled
    const int wg = (d & 7) * 128 + (d >> 3);
    const int e = wg >> 5, nb = wg & 31;
    const int cnt = ecnt[e];
    if (cnt == 0) return;
    const int n0 = nb * 64;
    const ushort_t* A = hact + (size_t)e * CAP_ * FF_;
    const float* B = w2 + (size_t)e * FF_ * HID_;

    __shared__ ushort_t As[256][72];
    __shared__ ushort_t Bs[64][72];
    const int tid = threadIdx.x;
    const int lane = tid & 63, wv = tid >> 6;
    const int lr = lane & 15, lg = lane >> 4;

    const int arow0 = tid >> 3, achk = tid & 7;
    const int bk0 = (tid & 15) * 2, bnq = tid >> 4;  // n-quad [0,16)
    const int bcol = n0 + bnq * 4;
    const int brow = bnq * 4;

    f32x4 acc[4][4];
#pragma unroll
    for (int i = 0; i < 4; i++)
#pragma unroll
        for (int j = 0; j < 4; j++) acc[i][j] = (f32x4){0.f, 0.f, 0.f, 0.f};

    for (int kb = 0; kb < FF_; kb += 64) {
        float4 bA0, bB0, bA1, bB1;
        bA0 = *(const float4*)(B + (size_t)(kb + bk0) * HID_ + bcol);
        bB0 = *(const float4*)(B + (size_t)(kb + bk0 + 1) * HID_ + bcol);
        bA1 = *(const float4*)(B + (size_t)(kb + 32 + bk0) * HID_ + bcol);
        bB1 = *(const float4*)(B + (size_t)(kb + 32 + bk0 + 1) * HID_ + bcol);
        uint4 areg[8];
#pragma unroll
        for (int i = 0; i < 8; i++)
            areg[i] = *(const uint4*)(A + (size_t)(arow0 + i * 32) * FF_ + kb + achk * 8);
        *(uint32_t*)&Bs[brow + 0][bk0] = cvtpk(bA0.x, bB0.x);
        *(uint32_t*)&Bs[brow + 1][bk0] = cvtpk(bA0.y, bB0.y);
        *(uint32_t*)&Bs[brow + 2][bk0] = cvtpk(bA0.z, bB0.z);
        *(uint32_t*)&Bs[brow + 3][bk0] = cvtpk(bA0.w, bB0.w);
        *(uint32_t*)&Bs[brow + 0][bk0 + 32] = cvtpk(bA1.x, bB1.x);
        *(uint32_t*)&Bs[brow + 1][bk0 + 32] = cvtpk(bA1.y, bB1.y);
        *(uint32_t*)&Bs[brow + 2][bk0 + 32] = cvtpk(bA1.z, bB1.z);
        *(uint32_t*)&Bs[brow + 3][bk0 + 32] = cvtpk(bA1.w, bB1.w);
#pragma unroll
        for (int i = 0; i < 8; i++)
            *(uint4*)&As[arow0 + i * 32][achk * 8] = areg[i];
        __syncthreads();
        short8 af[4][2], bfr[4][2];
#pragma unroll
        for (int mi = 0; mi < 4; mi++)
#pragma unroll
            for (int kk = 0; kk < 2; kk++)
                af[mi][kk] = *(const short8*)&As[wv * 64 + mi * 16 + lr][kk * 32 + lg * 8];
#pragma unroll
        for (int ni = 0; ni < 4; ni++)
#pragma unroll
            for (int kk = 0; kk < 2; kk++)
                bfr[ni][kk] = *(const short8*)&Bs[ni * 16 + lr][kk * 32 + lg * 8];
#pragma unroll
        for (int mi = 0; mi < 4; mi++)
#pragma unroll
            for (int ni = 0; ni < 4; ni++)
#pragma unroll
                for (int kk = 0; kk < 2; kk++)
                    acc[mi][ni] = mfma16(af[mi][kk], bfr[ni][kk], acc[mi][ni]);
        __syncthreads();
    }
#pragma unroll
    for (int mi = 0; mi < 4; mi++)
#pragma unroll
        for (int ni = 0; ni < 4; ni++)
#pragma unroll
            for (int r = 0; r < 4; r++) {
                int row = wv * 64 + mi * 16 + lg * 4 + r;
                int col = n0 + ni * 16 + lr;
                eo[((size_t)e * CAP_ + row) * HID_ + col] = f2bf(acc[mi][ni][r]);
            }
}

// ---------------- gate: logits (f64 accum, 4 chains) -> sigmoid -> top-4 ----------------
__global__ __launch_bounds__(256) void k_gate(
    const float* __restrict__ h2, const float* __restrict__ gw, const float* __restrict__ gb,
    int* __restrict__ topk_idx, float* __restrict__ topk_w)
{
    const int wv = threadIdx.x >> 6, lane = threadIdx.x & 63;
    const int t = blockIdx.x * 4 + wv;
    const float* x = h2 + (size_t)t * HID_;
    const int e = lane & 31;
    const int half = lane >> 5;
    double a0 = 0.0, a1 = 0.0, a2 = 0.0, a3 = 0.0;
    const int k0 = half * 1024;
    for (int k = 0; k < 1024; k += 4) {
        a0 += (double)x[k0 + k + 0] * (double)gw[(size_t)(k0 + k + 0) * NEXP_ + e];
        a1 += (double)x[k0 + k + 1] * (double)gw[(size_t)(k0 + k + 1) * NEXP_ + e];
        a2 += (double)x[k0 + k + 2] * (double)gw[(size_t)(k0 + k + 2) * NEXP_ + e];
        a3 += (double)x[k0 + k + 3] * (double)gw[(size_t)(k0 + k + 3) * NEXP_ + e];
    }
    double acc = (a0 + a1) + (a2 + a3);
    double other = __shfl_xor(acc, 32);
    double logit = acc + other;
    float score = (float)(1.0 / (1.0 + exp(-logit)));
    float sel = score + gb[e];

    int sel_idx[4]; float sel_w[4];
    unsigned picked = 0;
#pragma unroll
    for (int kk = 0; kk < 4; kk++) {
        float v = ((picked >> e) & 1u) ? -1e30f : sel;
        int vi = e;
#pragma unroll
        for (int m = 1; m < 32; m <<= 1) {
            float ov = __shfl_xor(v, m);
            int oi = __shfl_xor(vi, m);
            if (ov > v || (ov == v && oi < vi)) { v = ov; vi = oi; }
        }
        sel_idx[kk] = vi;
        sel_w[kk] = __shfl(score, vi);
        picked |= (1u << vi);
    }
    float wsum = sel_w[0] + sel_w[1] + sel_w[2] + sel_w[3];
    if (lane == 0) {
#pragma unroll
        for (int kk = 0; kk < 4; kk++) {
            topk_idx[t * 4 + kk] = sel_idx[kk];
            topk_w[t * 4 + kk] = sel_w[kk] / wsum;
        }
    }
}

// ---------------- deterministic capacity routing ----------------
__global__ __launch_bounds__(256) void k_route(
    const int* __restrict__ topk_idx, int* __restrict__ etok,
    int* __restrict__ ecnt, int* __restrict__ spos)
{
    const int e = blockIdx.x;
    __shared__ int wtot[4];
    __shared__ int basem;
    if (threadIdx.x == 0) basem = 0;
    __syncthreads();
    const int wv = threadIdx.x >> 6, lane = threadIdx.x & 63;
    for (int c = 0; c < 16; c++) {
        int slot = c * 256 + threadIdx.x;
        bool match = (topk_idx[slot] == e);
        unsigned long long b = __ballot(match);
        int pre = __popcll(b & ((1ull << lane) - 1ull));
        if (lane == 0) wtot[wv] = __popcll(b);
        __syncthreads();
        int off = basem;
        for (int ww = 0; ww < wv; ww++) off += wtot[ww];
        int pos = off + pre;
        if (match) {
            if (pos < CAP_) {
                etok[e * CAP_ + pos] = slot >> 2;
                spos[slot] = pos;
            } else {
                spos[slot] = -1;
            }
        }
        __syncthreads();
        if (threadIdx.x == 0) basem += wtot[0] + wtot[1] + wtot[2] + wtot[3];
        __syncthreads();
    }
    if (threadIdx.x == 0) ecnt[e] = min(basem, CAP_);
}

// ---------------- weighted scatter back to tokens ----------------
__global__ __launch_bounds__(256) void k_moe_out(
    const ushort_t* __restrict__ eo, const int* __restrict__ topk_idx,
    const float* __restrict__ topk_w, const int* __restrict__ spos,
    float* __restrict__ outp)
{
    const int t = blockIdx.x;
    float acc[8];
#pragma unroll
    for (int j = 0; j < 8; j++) acc[j] = 0.f;
    for (int kk = 0; kk < 4; kk++) {
        int slot = t * 4 + kk;
        int pos = spos[slot];
        if (pos < 0) continue;
        int e = topk_idx[slot];
        float wv = topk_w[slot];
        const ushort_t* er = eo + ((size_t)e * CAP_ + pos) * HID_;
#pragma unroll
        for (int j = 0; j < 8; j++) acc[j] += wv * bf2f(er[threadIdx.x + j * 256]);
    }
#pragma unroll
    for (int j = 0; j < 8; j++) outp[(size_t)t * HID_ + threadIdx.x + j * 256] = acc[j];
}

// ================== launcher ==================
extern "C" void kernel_launch(void* const* d_in, const int* in_sizes, int n_in,
                              void* d_out, int out_size, void* d_ws, size_t ws_size,
                              hipStream_t stream)
{
    (void)in_sizes; (void)n_in; (void)out_size; (void)ws_size;
    const int* positions = (const int*)d_in[0];
    const float* hs     = (const float*)d_in[1];
    const float* residp = (const float*)d_in[2];
    const float* w_qkv  = (const float*)d_in[3];
    const float* w_out  = (const float*)d_in[4];
    const float* q_ln   = (const float*)d_in[5];
    const float* k_ln   = (const float*)d_in[6];
    const float* op_w   = (const float*)d_in[7];
    const float* ffn_w  = (const float*)d_in[8];
    const float* gate_w = (const float*)d_in[9];
    const float* gate_b = (const float*)d_in[10];
    const float* w1     = (const float*)d_in[11];
    const float* w2     = (const float*)d_in[12];

    float* outp = (float*)d_out;
    float* res2 = outp + (size_t)T_ * HID_;

    char* p = (char*)d_ws;
    auto alloc = [&](size_t bytes) -> char* {
        char* r = p;
        p += (bytes + 255) & ~(size_t)255;
        return r;
    };
    float*    res   = (float*)alloc((size_t)T_ * HID_ * 4);
    ushort_t* h     = (ushort_t*)alloc((size_t)T_ * HID_ * 2);
    float*    qkv   = (float*)alloc((size_t)T_ * QKVN_ * 4);
    ushort_t* qr    = (ushort_t*)alloc((size_t)T_ * QS_ * 2);
    ushort_t* kc    = (ushort_t*)alloc((size_t)NKV_ * T_ * HD_ * 2);
    ushort_t* vT    = (ushort_t*)alloc((size_t)NKV_ * HD_ * T_ * 2);
    ushort_t* abuf  = (ushort_t*)alloc((size_t)T_ * HID_ * 2);
    float*    h2f   = (float*)alloc((size_t)T_ * HID_ * 4);
    ushort_t* h2b   = (ushort_t*)alloc((size_t)T_ * HID_ * 2);
    float*    cosb  = (float*)alloc((size_t)T_ * 32 * 4);
    float*    sinb  = (float*)alloc((size_t)T_ * 32 * 4);
    int*      tk_i  = (int*)alloc((size_t)T_ * 4 * 4);
    float*    tk_w  = (float*)alloc((size_t)T_ * 4 * 4);
    int*      etok  = (int*)alloc((size_t)NEXP_ * CAP_ * 4);
    int*      ecnt  = (int*)alloc((size_t)NEXP_ * 4);
    int*      spos  = (int*)alloc((size_t)T_ * 4 * 4);
    ushort_t* hact  = (ushort_t*)alloc((size_t)NEXP_ * CAP_ * FF_ * 2);
    ushort_t* eo    = (ushort_t*)alloc((size_t)NEXP_ * CAP_ * HID_ * 2);

    k_addnorm<<<T_, 256, 0, stream>>>(hs, residp, op_w, res, nullptr, h);
    k_rope_table<<<(T_ * 32 + 255) / 256, 256, 0, stream>>>(positions, cosb, sinb);
    k_gemm128<0><<<(T_ / 128) * (QKVN_ / 64), 256, 0, stream>>>(
        h, w_qkv, qkv, nullptr, QKVN_, HID_, QKVN_ / 64);
    k_qkv_post<<<T_, 256, 0, stream>>>(qkv, q_ln, k_ln, cosb, sinb, qr, kc, vT);
    k_attn<<<dim3(T_ / 64, NH_), 256, 0, stream>>>(qr, kc, vT, abuf);
    k_gemm128<1><<<(T_ / 128) * (HID_ / 64), 256, 0, stream>>>(
        abuf, w_out, res2, res, HID_, HID_, HID_ / 64);
    k_addnorm<<<T_, 256, 0, stream>>>(res2, nullptr, ffn_w, nullptr, h2f, h2b);
    k_gate<<<T_ / 4, 256, 0, stream>>>(h2f, gate_w, gate_b, tk_i, tk_w);
    k_route<<<NEXP_, 256, 0, stream>>>(tk_i, etok, ecnt, spos);
    k_moe_gu<<<28 * NEXP_, 256, 0, stream>>>(h2b, etok, ecnt, w1, hact);
    k_moe_w2<<<32 * NEXP_, 256, 0, stream>>>(hact, w2, ecnt, eo);
    k_moe_out<<<T_, 256, 0, stream>>>(eo, tk_i, tk_w, spos, outp);
}

// Round 16
// 713.440 us; speedup vs baseline: 1.0959x; 1.0959x over previous
//
#include <hip/hip_runtime.h>
#include <stdint.h>
#include <math.h>

typedef unsigned short ushort_t;
typedef __attribute__((ext_vector_type(8))) short short8;
typedef __attribute__((ext_vector_type(4))) float f32x4;

#define T_ 1024
#define HID_ 2048
#define NH_ 32
#define NKV_ 8
#define HD_ 64
#define QS_ 2048
#define KVS_ 512
#define QKVN_ 3072
#define NEXP_ 32
#define TOPK_ 4
#define FF_ 1792
#define FF2_ 3584
#define CAP_ 256
#define EPS_ 1e-5f
#define ATT_SCALE_ 0.125f

__device__ __forceinline__ ushort_t f2bf(float f) {
    uint32_t u = __builtin_bit_cast(uint32_t, f);
    u += 0x7FFFu + ((u >> 16) & 1u);
    return (ushort_t)(u >> 16);
}

__device__ __forceinline__ float bf2f(ushort_t u) {
    uint32_t x = ((uint32_t)u) << 16;
    return __builtin_bit_cast(float, x);
}

__device__ __forceinline__ f32x4 mfma16(short8 a, short8 b, f32x4 c) {
    return __builtin_amdgcn_mfma_f32_16x16x32_bf16(a, b, c, 0, 0, 0);
}

// pack two f32 -> {bf16(lo), bf16(hi)} in one uint32 (low half = lo)
__device__ __forceinline__ uint32_t cvtpk(float lo, float hi) {
    uint32_t r;
    asm("v_cvt_pk_bf16_f32 %0, %1, %2" : "=v"(r) : "v"(lo), "v"(hi));
    return r;
}

// ---------------- add + rmsnorm ----------------
__global__ __launch_bounds__(256) void k_addnorm(
    const float* __restrict__ a, const float* __restrict__ b,
    const float* __restrict__ w, float* __restrict__ res_out,
    float* __restrict__ hf, ushort_t* __restrict__ hb)
{
    __shared__ float sred[4];
    const int t = blockIdx.x;
    float x[8];
    float ss = 0.f;
#pragma unroll
    for (int i = 0; i < 8; i++) {
        int c = threadIdx.x + i * 256;
        float v = a[(size_t)t * HID_ + c];
        if (b) v += b[(size_t)t * HID_ + c];
        x[i] = v;
        ss += v * v;
    }
    ss += __shfl_xor(ss, 1);  ss += __shfl_xor(ss, 2);  ss += __shfl_xor(ss, 4);
    ss += __shfl_xor(ss, 8);  ss += __shfl_xor(ss, 16); ss += __shfl_xor(ss, 32);
    const int lane = threadIdx.x & 63, wv = threadIdx.x >> 6;
    if (lane == 0) sred[wv] = ss;
    __syncthreads();
    ss = sred[0] + sred[1] + sred[2] + sred[3];
    const float scale = rsqrtf(ss * (1.0f / HID_) + EPS_);
#pragma unroll
    for (int i = 0; i < 8; i++) {
        int c = threadIdx.x + i * 256;
        if (res_out) res_out[(size_t)t * HID_ + c] = x[i];
        float hv = x[i] * scale * w[c];
        if (hf) hf[(size_t)t * HID_ + c] = hv;
        hb[(size_t)t * HID_ + c] = f2bf(hv);
    }
}

// ---------------- rope tables ----------------
__global__ __launch_bounds__(256) void k_rope_table(const int* __restrict__ positions,
                                                    float* __restrict__ cosb, float* __restrict__ sinb)
{
    int idx = blockIdx.x * 256 + threadIdx.x;
    if (idx >= T_ * 32) return;
    int t = idx >> 5, f = idx & 31;
    double invf = pow(1.0e6, -((double)f) / 32.0);
    double ang = (double)positions[t] * invf;
    cosb[idx] = (float)cos(ang);
    sinb[idx] = (float)sin(ang);
}

// ---------------- q/k head-rmsnorm + rope, v transpose ----------------
__global__ __launch_bounds__(256) void k_qkv_post(
    const float* __restrict__ qkv, const float* __restrict__ qw, const float* __restrict__ kw,
    const float* __restrict__ cosb, const float* __restrict__ sinb,
    ushort_t* __restrict__ qr, ushort_t* __restrict__ kc, ushort_t* __restrict__ vT)
{
    const int t = blockIdx.x;
    const int wv = threadIdx.x >> 6, lane = threadIdx.x & 63;
    const float* row = qkv + (size_t)t * QKVN_;
    const float c = cosb[t * 32 + (lane & 31)];
    const float s = sinb[t * 32 + (lane & 31)];
#pragma unroll
    for (int i = 0; i < 8; i++) {
        int hh = wv + i * 4;
        float x = row[hh * 64 + lane];
        float ss = x * x;
        ss += __shfl_xor(ss, 1); ss += __shfl_xor(ss, 2); ss += __shfl_xor(ss, 4);
        ss += __shfl_xor(ss, 8); ss += __shfl_xor(ss, 16); ss += __shfl_xor(ss, 32);
        float xn = x * rsqrtf(ss * (1.0f / 64.0f) + EPS_) * qw[lane];
        float other = __shfl_xor(xn, 32);
        float o = (lane < 32) ? (xn * c - other * s) : (xn * c + other * s);
        qr[(size_t)t * QS_ + hh * 64 + lane] = f2bf(o);
    }
#pragma unroll
    for (int i = 0; i < 2; i++) {
        int kh = wv * 2 + i;
        float x = row[QS_ + kh * 64 + lane];
        float ss = x * x;
        ss += __shfl_xor(ss, 1); ss += __shfl_xor(ss, 2); ss += __shfl_xor(ss, 4);
        ss += __shfl_xor(ss, 8); ss += __shfl_xor(ss, 16); ss += __shfl_xor(ss, 32);
        float xn = x * rsqrtf(ss * (1.0f / 64.0f) + EPS_) * kw[lane];
        float other = __shfl_xor(xn, 32);
        float o = (lane < 32) ? (xn * c - other * s) : (xn * c + other * s);
        kc[((size_t)kh * T_ + t) * 64 + lane] = f2bf(o);
    }
#pragma unroll
    for (int i = 0; i < 2; i++) {
        int idx = threadIdx.x + i * 256;
        int kh = idx >> 6, d = idx & 63;
        vT[((size_t)kh * 64 + d) * T_ + t] = f2bf(row[QS_ + KVS_ + idx]);
    }
}

// ---------------- causal GQA flash attention ----------------
__global__ __launch_bounds__(256) void k_attn(
    const ushort_t* __restrict__ qr, const ushort_t* __restrict__ kc,
    const ushort_t* __restrict__ vT, ushort_t* __restrict__ aout)
{
    __shared__ float p_lds[4][16][36];
    const int head = blockIdx.y;
    const int qb = blockIdx.x * 64;
    const int wv = threadIdx.x >> 6, lane = threadIdx.x & 63;
    const int lr = lane & 15, lg = lane >> 4;
    const int kvh = head >> 2;
    const int qbase = qb + wv * 16;

    const ushort_t* qp = qr + (size_t)(qbase + lr) * QS_ + head * 64 + lg * 8;
    short8 qf0 = *(const short8*)qp;
    short8 qf1 = *(const short8*)(qp + 32);

    f32x4 o[4];
#pragma unroll
    for (int i = 0; i < 4; i++) o[i] = (f32x4){0.f, 0.f, 0.f, 0.f};
    float mrow[4] = {-INFINITY, -INFINITY, -INFINITY, -INFINITY};
    float lrow[4] = {0.f, 0.f, 0.f, 0.f};

    const int ntile = ((qbase + 15) >> 5) + 1;
    for (int tt = 0; tt < ntile; tt++) {
        const int kv0 = tt * 32;
        const ushort_t* kp = kc + ((size_t)kvh * T_ + kv0) * 64;
        short8 b00 = *(const short8*)(kp + lr * 64 + lg * 8);
        short8 b01 = *(const short8*)(kp + lr * 64 + 32 + lg * 8);
        short8 b10 = *(const short8*)(kp + (16 + lr) * 64 + lg * 8);
        short8 b11 = *(const short8*)(kp + (16 + lr) * 64 + 32 + lg * 8);
        f32x4 s0 = {0.f, 0.f, 0.f, 0.f}, s1 = {0.f, 0.f, 0.f, 0.f};
        s0 = mfma16(qf0, b00, s0); s0 = mfma16(qf1, b01, s0);
        s1 = mfma16(qf0, b10, s1); s1 = mfma16(qf1, b11, s1);

        float p0[4], p1[4], alpha[4];
#pragma unroll
        for (int r = 0; r < 4; r++) {
            int qrow = qbase + lg * 4 + r;
            float v0 = (kv0 + lr <= qrow) ? s0[r] * ATT_SCALE_ : -INFINITY;
            float v1 = (kv0 + 16 + lr <= qrow) ? s1[r] * ATT_SCALE_ : -INFINITY;
            float mx = fmaxf(v0, v1);
            mx = fmaxf(mx, __shfl_xor(mx, 1));
            mx = fmaxf(mx, __shfl_xor(mx, 2));
            mx = fmaxf(mx, __shfl_xor(mx, 4));
            mx = fmaxf(mx, __shfl_xor(mx, 8));
            float mn = fmaxf(mrow[r], mx);
            float al = (mrow[r] == -INFINITY) ? 0.f : __expf(mrow[r] - mn);
            float pv0 = (v0 == -INFINITY) ? 0.f : __expf(v0 - mn);
            float pv1 = (v1 == -INFINITY) ? 0.f : __expf(v1 - mn);
            float ps = pv0 + pv1;
            ps += __shfl_xor(ps, 1); ps += __shfl_xor(ps, 2);
            ps += __shfl_xor(ps, 4); ps += __shfl_xor(ps, 8);
            lrow[r] = lrow[r] * al + ps;
            mrow[r] = mn;
            alpha[r] = al; p0[r] = pv0; p1[r] = pv1;
        }
#pragma unroll
        for (int r = 0; r < 4; r++) {
            p_lds[wv][lg * 4 + r][lr] = p0[r];
            p_lds[wv][lg * 4 + r][16 + lr] = p1[r];
            o[0][r] *= alpha[r]; o[1][r] *= alpha[r];
            o[2][r] *= alpha[r]; o[3][r] *= alpha[r];
        }
        asm volatile("s_waitcnt lgkmcnt(0)" ::: "memory");
        float4 pa0 = *(const float4*)&p_lds[wv][lr][lg * 8];
        float4 pa1 = *(const float4*)&p_lds[wv][lr][lg * 8 + 4];
        short8 pf;
        pf[0] = (short)f2bf(pa0.x); pf[1] = (short)f2bf(pa0.y);
        pf[2] = (short)f2bf(pa0.z); pf[3] = (short)f2bf(pa0.w);
        pf[4] = (short)f2bf(pa1.x); pf[5] = (short)f2bf(pa1.y);
        pf[6] = (short)f2bf(pa1.z); pf[7] = (short)f2bf(pa1.w);
#pragma unroll
        for (int dg = 0; dg < 4; dg++) {
            short8 vf = *(const short8*)(vT + ((size_t)(kvh * 64 + dg * 16 + lr)) * T_ + kv0 + lg * 8);
            o[dg] = mfma16(pf, vf, o[dg]);
        }
    }
#pragma unroll
    for (int dg = 0; dg < 4; dg++)
#pragma unroll
        for (int r = 0; r < 4; r++)
            aout[(size_t)(qbase + lg * 4 + r) * HID_ + head * 64 + dg * 16 + lr] =
                f2bf(o[dg][r] / lrow[r]);
}

// ---------------- 128x64 GEMM, BK=128, in-phase staging ----------------
// 1D grid with XCD swizzle. MODE 0: C = acc ; MODE 1: C = acc + resid
template <int MODE>
__global__ __launch_bounds__(256) void k_gemm128(
    const ushort_t* __restrict__ A, const float* __restrict__ B,
    float* __restrict__ C, const float* __restrict__ resid, int N, int K, int nnb)
{
    const int nwg8 = (gridDim.x >> 3);
    const int d = blockIdx.x;
    const int wg = (d & 7) * nwg8 + (d >> 3);
    const int mbase = (wg / nnb) * 128, nbase = (wg % nnb) * 64;

    __shared__ ushort_t As[128][136];  // 128 x 128k (+8 pad)
    __shared__ ushort_t Bs[64][136];   // [n][k]
    const int tid = threadIdx.x;
    const int lane = tid & 63, wv = tid >> 6;
    const int lr = lane & 15, lg = lane >> 4;
    const int wm = wv >> 1, wn = wv & 1;

    f32x4 acc[4][2];
#pragma unroll
    for (int i = 0; i < 4; i++)
#pragma unroll
        for (int j = 0; j < 2; j++) acc[i][j] = (f32x4){0.f, 0.f, 0.f, 0.f};

    const int arow0 = tid >> 4, achk = tid & 15;     // 16 base rows x 16 chunks
    const int bk0 = (tid & 15) * 2, bnq = tid >> 4;  // k-pair, n-quad [0,16)
    const int bcol = nbase + bnq * 4;
    const int brow = bnq * 4;

    for (int kb = 0; kb < K; kb += 128) {
        // B: 4 k-strips, loaded & converted sequentially (in-phase)
#pragma unroll
        for (int ks = 0; ks < 4; ks++) {
            const int ko = ks * 32;
            float4 bA = *(const float4*)(B + (size_t)(kb + ko + bk0) * N + bcol);
            float4 bB = *(const float4*)(B + (size_t)(kb + ko + bk0 + 1) * N + bcol);
            *(uint32_t*)&Bs[brow + 0][bk0 + ko] = cvtpk(bA.x, bB.x);
            *(uint32_t*)&Bs[brow + 1][bk0 + ko] = cvtpk(bA.y, bB.y);
            *(uint32_t*)&Bs[brow + 2][bk0 + ko] = cvtpk(bA.z, bB.z);
            *(uint32_t*)&Bs[brow + 3][bk0 + ko] = cvtpk(bA.w, bB.w);
        }
        // A: 8 row-groups of 16
        {
            uint4 areg[8];
#pragma unroll
            for (int i = 0; i < 8; i++)
                areg[i] = *(const uint4*)(A + (size_t)(mbase + arow0 + i * 16) * K + kb + achk * 8);
#pragma unroll
            for (int i = 0; i < 8; i++)
                *(uint4*)&As[arow0 + i * 16][achk * 8] = areg[i];
        }
        __syncthreads();
#pragma unroll
        for (int kk = 0; kk < 4; kk++) {
            short8 af[4], bfr[2];
#pragma unroll
            for (int mi = 0; mi < 4; mi++)
                af[mi] = *(const short8*)&As[wm * 64 + mi * 16 + lr][kk * 32 + lg * 8];
#pragma unroll
            for (int ni = 0; ni < 2; ni++)
                bfr[ni] = *(const short8*)&Bs[wn * 32 + ni * 16 + lr][kk * 32 + lg * 8];
#pragma unroll
            for (int mi = 0; mi < 4; mi++)
#pragma unroll
                for (int ni = 0; ni < 2; ni++)
                    acc[mi][ni] = mfma16(af[mi], bfr[ni], acc[mi][ni]);
        }
        __syncthreads();
    }
#pragma unroll
    for (int mi = 0; mi < 4; mi++)
#pragma unroll
        for (int ni = 0; ni < 2; ni++)
#pragma unroll
            for (int r = 0; r < 4; r++) {
                int row = mbase + wm * 64 + mi * 16 + lg * 4 + r;
                int col = nbase + wn * 32 + ni * 16 + lr;
                float v = acc[mi][ni][r];
                if (MODE == 1) v += resid[(size_t)row * N + col];
                C[(size_t)row * N + col] = v;
            }
}

// ---------------- MoE gu GEMM: M=256/expert, N=32g+32u, BK=64 ----------------
// Zero cross-barrier register state (R6/R9-proven).
__global__ __launch_bounds__(256) void k_moe_gu(
    const ushort_t* __restrict__ h2b, const int* __restrict__ etok,
    const int* __restrict__ ecnt, const float* __restrict__ w1,
    ushort_t* __restrict__ hact)
{
    const int d = blockIdx.x;                    // 1792 = 32e * 56n, XCD-swizzled
    const int wg = (d & 7) * 224 + (d >> 3);
    const int e = wg / 56, ny = wg - e * 56;
    const int cnt = ecnt[e];
    if (cnt == 0) return;
    const int ng0 = ny * 32;
    const float* B = w1 + (size_t)e * HID_ * FF2_;

    __shared__ ushort_t As[256][72];  // 256 x 64k (+8 pad)
    __shared__ ushort_t Bs[64][72];   // rows 0-31: g, 32-63: u
    const int tid = threadIdx.x;
    const int lane = tid & 63, wv = tid >> 6;
    const int lr = lane & 15, lg = lane >> 4;

    const int arow0 = tid >> 3, achk = tid & 7;  // 32 base-rows x 8 k-chunks
    int tok[8];
#pragma unroll
    for (int i = 0; i < 8; i++) {
        int r = arow0 + i * 32;
        tok[i] = (r < cnt) ? etok[e * CAP_ + r] : 0;
    }
    const int half = tid >> 7;                   // 0: g, 1: u
    const int t7 = tid & 127;
    const int bk0 = (t7 & 15) * 2, bnq = t7 >> 4;  // k-pair, n-quad [0,8)
    const size_t bcol = (half ? FF_ : 0) + ng0 + bnq * 4;
    const int brow = half * 32 + bnq * 4;

    f32x4 ag[4][2], au[4][2];
#pragma unroll
    for (int i = 0; i < 4; i++)
#pragma unroll
        for (int j = 0; j < 2; j++) { ag[i][j] = (f32x4){0.f,0.f,0.f,0.f}; au[i][j] = (f32x4){0.f,0.f,0.f,0.f}; }

    for (int kb = 0; kb < HID_; kb += 64) {
        // issue all loads, stage, one round-trip per 64-k step
        float4 bA0, bB0, bA1, bB1;
        bA0 = *(const float4*)(B + (size_t)(kb + bk0) * FF2_ + bcol);
        bB0 = *(const float4*)(B + (size_t)(kb + bk0 + 1) * FF2_ + bcol);
        bA1 = *(const float4*)(B + (size_t)(kb + 32 + bk0) * FF2_ + bcol);
        bB1 = *(const float4*)(B + (size_t)(kb + 32 + bk0 + 1) * FF2_ + bcol);
        uint4 areg[8];
#pragma unroll
        for (int i = 0; i < 8; i++)
            areg[i] = *(const uint4*)(h2b + (size_t)tok[i] * HID_ + kb + achk * 8);
        *(uint32_t*)&Bs[brow + 0][bk0] = cvtpk(bA0.x, bB0.x);
        *(uint32_t*)&Bs[brow + 1][bk0] = cvtpk(bA0.y, bB0.y);
        *(uint32_t*)&Bs[brow + 2][bk0] = cvtpk(bA0.z, bB0.z);
        *(uint32_t*)&Bs[brow + 3][bk0] = cvtpk(bA0.w, bB0.w);
        *(uint32_t*)&Bs[brow + 0][bk0 + 32] = cvtpk(bA1.x, bB1.x);
        *(uint32_t*)&Bs[brow + 1][bk0 + 32] = cvtpk(bA1.y, bB1.y);
        *(uint32_t*)&Bs[brow + 2][bk0 + 32] = cvtpk(bA1.z, bB1.z);
        *(uint32_t*)&Bs[brow + 3][bk0 + 32] = cvtpk(bA1.w, bB1.w);
#pragma unroll
        for (int i = 0; i < 8; i++)
            *(uint4*)&As[arow0 + i * 32][achk * 8] = areg[i];
        __syncthreads();
        short8 af[4][2], bg[2][2], bu[2][2];
#pragma unroll
        for (int mi = 0; mi < 4; mi++)
#pragma unroll
            for (int kk = 0; kk < 2; kk++)
                af[mi][kk] = *(const short8*)&As[wv * 64 + mi * 16 + lr][kk * 32 + lg * 8];
#pragma unroll
        for (int nj = 0; nj < 2; nj++)
#pragma unroll
            for (int kk = 0; kk < 2; kk++) {
                bg[nj][kk] = *(const short8*)&Bs[nj * 16 + lr][kk * 32 + lg * 8];
                bu[nj][kk] = *(const short8*)&Bs[32 + nj * 16 + lr][kk * 32 + lg * 8];
            }
#pragma unroll
        for (int mi = 0; mi < 4; mi++)
#pragma unroll
            for (int nj = 0; nj < 2; nj++)
#pragma unroll
                for (int kk = 0; kk < 2; kk++) {
                    ag[mi][nj] = mfma16(af[mi][kk], bg[nj][kk], ag[mi][nj]);
                    au[mi][nj] = mfma16(af[mi][kk], bu[nj][kk], au[mi][nj]);
                }
        __syncthreads();
    }
#pragma unroll
    for (int mi = 0; mi < 4; mi++)
#pragma unroll
        for (int nj = 0; nj < 2; nj++)
#pragma unroll
            for (int r = 0; r < 4; r++) {
                int row = wv * 64 + mi * 16 + lg * 4 + r;
                int col = ng0 + nj * 16 + lr;
                float g = ag[mi][nj][r], u = au[mi][nj][r];
                float hval = (g / (1.0f + __expf(-g))) * u;
                hact[((size_t)e * CAP_ + row) * FF_ + col] = f2bf(hval);
            }
}

// ---------------- MoE w2 GEMM: M=256/expert, N-tile 64, BK=64 ----------------
__global__ __launch_bounds__(256) void k_moe_w2(
    const ushort_t* __restrict__ hact, const float* __restrict__ w2,
    const int* __restrict__ ecnt, ushort_t* __restrict__ eo)
{
    const int d = blockIdx.x;                    // 1024 = 32e * 32n, XCD-swizzled
    const int wg = (d & 7) * 128 + (d >> 3);
    const int e = wg >> 5, nb = wg & 31;
    const int cnt = ecnt[e];
    if (cnt == 0) return;
    const int n0 = nb * 64;
    const ushort_t* A = hact + (size_t)e * CAP_ * FF_;
    const float* B = w2 + (size_t)e * FF_ * HID_;

    __shared__ ushort_t As[256][72];
    __shared__ ushort_t Bs[64][72];
    const int tid = threadIdx.x;
    const int lane = tid & 63, wv = tid >> 6;
    const int lr = lane & 15, lg = lane >> 4;

    const int arow0 = tid >> 3, achk = tid & 7;
    const int bk0 = (tid & 15) * 2, bnq = tid >> 4;  // n-quad [0,16)
    const int bcol = n0 + bnq * 4;
    const int brow = bnq * 4;

    f32x4 acc[4][4];
#pragma unroll
    for (int i = 0; i < 4; i++)
#pragma unroll
        for (int j = 0; j < 4; j++) acc[i][j] = (f32x4){0.f, 0.f, 0.f, 0.f};

    for (int kb = 0; kb < FF_; kb += 64) {
        float4 bA0, bB0, bA1, bB1;
        bA0 = *(const float4*)(B + (size_t)(kb + bk0) * HID_ + bcol);
        bB0 = *(const float4*)(B + (size_t)(kb + bk0 + 1) * HID_ + bcol);
        bA1 = *(const float4*)(B + (size_t)(kb + 32 + bk0) * HID_ + bcol);
        bB1 = *(const float4*)(B + (size_t)(kb + 32 + bk0 + 1) * HID_ + bcol);
        uint4 areg[8];
#pragma unroll
        for (int i = 0; i < 8; i++)
            areg[i] = *(const uint4*)(A + (size_t)(arow0 + i * 32) * FF_ + kb + achk * 8);
        *(uint32_t*)&Bs[brow + 0][bk0] = cvtpk(bA0.x, bB0.x);
        *(uint32_t*)&Bs[brow + 1][bk0] = cvtpk(bA0.y, bB0.y);
        *(uint32_t*)&Bs[brow + 2][bk0] = cvtpk(bA0.z, bB0.z);
        *(uint32_t*)&Bs[brow + 3][bk0] = cvtpk(bA0.w, bB0.w);
        *(uint32_t*)&Bs[brow + 0][bk0 + 32] = cvtpk(bA1.x, bB1.x);
        *(uint32_t*)&Bs[brow + 1][bk0 + 32] = cvtpk(bA1.y, bB1.y);
        *(uint32_t*)&Bs[brow + 2][bk0 + 32] = cvtpk(bA1.z, bB1.z);
        *(uint32_t*)&Bs[brow + 3][bk0 + 32] = cvtpk(bA1.w, bB1.w);
#pragma unroll
        for (int i = 0; i < 8; i++)
            *(uint4*)&As[arow0 + i * 32][achk * 8] = areg[i];
        __syncthreads();
        short8 af[4][2], bfr[4][2];
#pragma unroll
        for (int mi = 0; mi < 4; mi++)
#pragma unroll
            for (int kk = 0; kk < 2; kk++)
                af[mi][kk] = *(const short8*)&As[wv * 64 + mi * 16 + lr][kk * 32 + lg * 8];
#pragma unroll
        for (int ni = 0; ni < 4; ni++)
#pragma unroll
            for (int kk = 0; kk < 2; kk++)
                bfr[ni][kk] = *(const short8*)&Bs[ni * 16 + lr][kk * 32 + lg * 8];
#pragma unroll
        for (int mi = 0; mi < 4; mi++)
#pragma unroll
            for (int ni = 0; ni < 4; ni++)
#pragma unroll
                for (int kk = 0; kk < 2; kk++)
                    acc[mi][ni] = mfma16(af[mi][kk], bfr[ni][kk], acc[mi][ni]);
        __syncthreads();
    }
#pragma unroll
    for (int mi = 0; mi < 4; mi++)
#pragma unroll
        for (int ni = 0; ni < 4; ni++)
#pragma unroll
            for (int r = 0; r < 4; r++) {
                int row = wv * 64 + mi * 16 + lg * 4 + r;
                int col = n0 + ni * 16 + lr;
                eo[((size_t)e * CAP_ + row) * HID_ + col] = f2bf(acc[mi][ni][r]);
            }
}

// ---------------- gate: logits (f64 accum, 4 chains) -> sigmoid -> top-4 ----------------
__global__ __launch_bounds__(256) void k_gate(
    const float* __restrict__ h2, const float* __restrict__ gw, const float* __restrict__ gb,
    int* __restrict__ topk_idx, float* __restrict__ topk_w)
{
    const int wv = threadIdx.x >> 6, lane = threadIdx.x & 63;
    const int t = blockIdx.x * 4 + wv;
    const float* x = h2 + (size_t)t * HID_;
    const int e = lane & 31;
    const int half = lane >> 5;
    double a0 = 0.0, a1 = 0.0, a2 = 0.0, a3 = 0.0;
    const int k0 = half * 1024;
    for (int k = 0; k < 1024; k += 4) {
        a0 += (double)x[k0 + k + 0] * (double)gw[(size_t)(k0 + k + 0) * NEXP_ + e];
        a1 += (double)x[k0 + k + 1] * (double)gw[(size_t)(k0 + k + 1) * NEXP_ + e];
        a2 += (double)x[k0 + k + 2] * (double)gw[(size_t)(k0 + k + 2) * NEXP_ + e];
        a3 += (double)x[k0 + k + 3] * (double)gw[(size_t)(k0 + k + 3) * NEXP_ + e];
    }
    double acc = (a0 + a1) + (a2 + a3);
    double other = __shfl_xor(acc, 32);
    double logit = acc + other;
    float score = (float)(1.0 / (1.0 + exp(-logit)));
    float sel = score + gb[e];

    int sel_idx[4]; float sel_w[4];
    unsigned picked = 0;
#pragma unroll
    for (int kk = 0; kk < 4; kk++) {
        float v = ((picked >> e) & 1u) ? -1e30f : sel;
        int vi = e;
#pragma unroll
        for (int m = 1; m < 32; m <<= 1) {
            float ov = __shfl_xor(v, m);
            int oi = __shfl_xor(vi, m);
            if (ov > v || (ov == v && oi < vi)) { v = ov; vi = oi; }
        }
        sel_idx[kk] = vi;
        sel_w[kk] = __shfl(score, vi);
        picked |= (1u << vi);
    }
    float wsum = sel_w[0] + sel_w[1] + sel_w[2] + sel_w[3];
    if (lane == 0) {
#pragma unroll
        for (int kk = 0; kk < 4; kk++) {
            topk_idx[t * 4 + kk] = sel_idx[kk];
            topk_w[t * 4 + kk] = sel_w[kk] / wsum;
        }
    }
}

// ---------------- deterministic capacity routing ----------------
__global__ __launch_bounds__(256) void k_route(
    const int* __restrict__ topk_idx, int* __restrict__ etok,
    int* __restrict__ ecnt, int* __restrict__ spos)
{
    const int e = blockIdx.x;
    __shared__ int wtot[4];
    __shared__ int basem;
    if (threadIdx.x == 0) basem = 0;
    __syncthreads();
    const int wv = threadIdx.x >> 6, lane = threadIdx.x & 63;
    for (int c = 0; c < 16; c++) {
        int slot = c * 256 + threadIdx.x;
        bool match = (topk_idx[slot] == e);
        unsigned long long b = __ballot(match);
        int pre = __popcll(b & ((1ull << lane) - 1ull));
        if (lane == 0) wtot[wv] = __popcll(b);
        __syncthreads();
        int off = basem;
        for (int ww = 0; ww < wv; ww++) off += wtot[ww];
        int pos = off + pre;
        if (match) {
            if (pos < CAP_) {
                etok[e * CAP_ + pos] = slot >> 2;
                spos[slot] = pos;
            } else {
                spos[slot] = -1;
            }
        }
        __syncthreads();
        if (threadIdx.x == 0) basem += wtot[0] + wtot[1] + wtot[2] + wtot[3];
        __syncthreads();
    }
    if (threadIdx.x == 0) ecnt[e] = min(basem, CAP_);
}

// ---------------- weighted scatter back to tokens ----------------
__global__ __launch_bounds__(256) void k_moe_out(
    const ushort_t* __restrict__ eo, const int* __restrict__ topk_idx,
    const float* __restrict__ topk_w, const int* __restrict__ spos,
    float* __restrict__ outp)
{
    const int t = blockIdx.x;
    float acc[8];
#pragma unroll
    for (int j = 0; j < 8; j++) acc[j] = 0.f;
    for (int kk = 0; kk < 4; kk++) {
        int slot = t * 4 + kk;
        int pos = spos[slot];
        if (pos < 0) continue;
        int e = topk_idx[slot];
        float wv = topk_w[slot];
        const ushort_t* er = eo + ((size_t)e * CAP_ + pos) * HID_;
#pragma unroll
        for (int j = 0; j < 8; j++) acc[j] += wv * bf2f(er[threadIdx.x + j * 256]);
    }
#pragma unroll
    for (int j = 0; j < 8; j++) outp[(size_t)t * HID_ + threadIdx.x + j * 256] = acc[j];
}

// ================== launcher ==================
extern "C" void kernel_launch(void* const* d_in, const int* in_sizes, int n_in,
                              void* d_out, int out_size, void* d_ws, size_t ws_size,
                              hipStream_t stream)
{
    (void)in_sizes; (void)n_in; (void)out_size; (void)ws_size;
    const int* positions = (const int*)d_in[0];
    const float* hs     = (const float*)d_in[1];
    const float* residp = (const float*)d_in[2];
    const float* w_qkv  = (const float*)d_in[3];
    const float* w_out  = (const float*)d_in[4];
    const float* q_ln   = (const float*)d_in[5];
    const float* k_ln   = (const float*)d_in[6];
    const float* op_w   = (const float*)d_in[7];
    const float* ffn_w  = (const float*)d_in[8];
    const float* gate_w = (const float*)d_in[9];
    const float* gate_b = (const float*)d_in[10];
    const float* w1     = (const float*)d_in[11];
    const float* w2     = (const float*)d_in[12];

    float* outp = (float*)d_out;
    float* res2 = outp + (size_t)T_ * HID_;

    char* p = (char*)d_ws;
    auto alloc = [&](size_t bytes) -> char* {
        char* r = p;
        p += (bytes + 255) & ~(size_t)255;
        return r;
    };
    float*    res   = (float*)alloc((size_t)T_ * HID_ * 4);
    ushort_t* h     = (ushort_t*)alloc((size_t)T_ * HID_ * 2);
    float*    qkv   = (float*)alloc((size_t)T_ * QKVN_ * 4);
    ushort_t* qr    = (ushort_t*)alloc((size_t)T_ * QS_ * 2);
    ushort_t* kc    = (ushort_t*)alloc((size_t)NKV_ * T_ * HD_ * 2);
    ushort_t* vT    = (ushort_t*)alloc((size_t)NKV_ * HD_ * T_ * 2);
    ushort_t* abuf  = (ushort_t*)alloc((size_t)T_ * HID_ * 2);
    float*    h2f   = (float*)alloc((size_t)T_ * HID_ * 4);
    ushort_t* h2b   = (ushort_t*)alloc((size_t)T_ * HID_ * 2);
    float*    cosb  = (float*)alloc((size_t)T_ * 32 * 4);
    float*    sinb  = (float*)alloc((size_t)T_ * 32 * 4);
    int*      tk_i  = (int*)alloc((size_t)T_ * 4 * 4);
    float*    tk_w  = (float*)alloc((size_t)T_ * 4 * 4);
    int*      etok  = (int*)alloc((size_t)NEXP_ * CAP_ * 4);
    int*      ecnt  = (int*)alloc((size_t)NEXP_ * 4);
    int*      spos  = (int*)alloc((size_t)T_ * 4 * 4);
    ushort_t* hact  = (ushort_t*)alloc((size_t)NEXP_ * CAP_ * FF_ * 2);
    ushort_t* eo    = (ushort_t*)alloc((size_t)NEXP_ * CAP_ * HID_ * 2);

    k_addnorm<<<T_, 256, 0, stream>>>(hs, residp, op_w, res, nullptr, h);
    k_rope_table<<<(T_ * 32 + 255) / 256, 256, 0, stream>>>(positions, cosb, sinb);
    k_gemm128<0><<<(T_ / 128) * (QKVN_ / 64), 256, 0, stream>>>(
        h, w_qkv, qkv, nullptr, QKVN_, HID_, QKVN_ / 64);
    k_qkv_post<<<T_, 256, 0, stream>>>(qkv, q_ln, k_ln, cosb, sinb, qr, kc, vT);
    k_attn<<<dim3(T_ / 64, NH_), 256, 0, stream>>>(qr, kc, vT, abuf);
    k_gemm128<1><<<(T_ / 128) * (HID_ / 64), 256, 0, stream>>>(
        abuf, w_out, res2, res, HID_, HID_, HID_ / 64);
    k_addnorm<<<T_, 256, 0, stream>>>(res2, nullptr, ffn_w, nullptr, h2f, h2b);
    k_gate<<<T_ / 4, 256, 0, stream>>>(h2f, gate_w, gate_b, tk_i, tk_w);
    k_route<<<NEXP_, 256, 0, stream>>>(tk_i, etok, ecnt, spos);
    k_moe_gu<<<56 * NEXP_, 256, 0, stream>>>(h2b, etok, ecnt, w1, hact);
    k_moe_w2<<<32 * NEXP_, 256, 0, stream>>>(hact, w2, ecnt, eo);
    k_moe_out<<<T_, 256, 0, stream>>>(eo, tk_i, tk_w, spos, outp);
}